// Round 2
// baseline (652.891 us; speedup 1.0000x reference)
//
#include <hip/hip_runtime.h>
#include <hip/hip_bf16.h>
#include <stdint.h>

// out[b,o] = sum_{k,i} hyp[b,k] * h[b,i] * W2[k, i*256+o] + sum_i h[b,i]*b2[i*256+o] + bias[o]
// GEMM A[4096 x 131328] * B[131328 x 256]; A generated on the fly in LDS,
// B = W2 flat (bf16, transposed+swizzled tiles, packed once).
// ws: [0,8MB) hyp fp32; [8MB,+67.2MB) packed B tiles.

typedef __bf16 bf16x8 __attribute__((ext_vector_type(8)));
typedef float  f32x4  __attribute__((ext_vector_type(4)));

#define KTILES      2052
#define TILE_BYTES  32768    // 256 cols * 64 k * 2 B

// ---------------- out = bias ----------------
__global__ void k_init_out(const float* __restrict__ bias, float* __restrict__ out) {
    int idx = blockIdx.x * 256 + threadIdx.x;
    out[idx] = bias[idx & 255];
}

// ---------------- hyp = relu(z @ W1 + b1), fp32 ----------------
__global__ void k_hyp(const float* __restrict__ z, const float* __restrict__ W1,
                      const float* __restrict__ b1, float* __restrict__ hyp) {
    __shared__ float zs[128];
    int b = blockIdx.x;
    int j = threadIdx.x;
    if (j < 128) zs[j] = z[b * 128 + j];
    __syncthreads();
    float a0 = b1[j], a1 = b1[j + 256];
#pragma unroll 8
    for (int c = 0; c < 128; ++c) {
        float zc = zs[c];
        a0 += zc * W1[c * 512 + j];
        a1 += zc * W1[c * 512 + j + 256];
    }
    hyp[b * 512 + j]       = a0 > 0.f ? a0 : 0.f;
    hyp[b * 512 + j + 256] = a1 > 0.f ? a1 : 0.f;
}

// ---------------- pack W2 (+b2) -> bf16 transposed+swizzled tiles ----------------
// element (kk, o) of tile t at byte (o*128 + kk*2) ^ ((o&7)<<4)
__global__ void k_pack(const float* __restrict__ W2, const float* __restrict__ b2,
                       uint16_t* __restrict__ Bp) {
    int t = blockIdx.x;
    int o = threadIdx.x;
    long row0 = (long)t * 64;
    const float* src = (t < 2048) ? (W2 + row0 * 256) : (b2 + (row0 - 131072) * 256);
    char* dst = (char*)Bp + (size_t)t * TILE_BYTES;
    int swz = (o & 7) << 4;
#pragma unroll
    for (int k8 = 0; k8 < 8; ++k8) {
        bf16x8 v;
#pragma unroll
        for (int q = 0; q < 8; ++q)
            v[q] = (__bf16)src[(k8 * 8 + q) * 256 + o];
        *(bf16x8*)(dst + ((o * 128 + k8 * 16) ^ swz)) = v;
    }
}

// ---------------- main GEMM: BM=128, BN=128, BK=64, 4 waves ----------------
// 2-phase double-buffered pipeline; grid 512 = 8 XCD-affine K-slabs x 32 mt x 2 nt;
// exactly 2 blocks/CU (64KB LDS), single launch wave.
__global__ __launch_bounds__(256) void k_gemm(
        const float* __restrict__ h, const float* __restrict__ hyp,
        const uint16_t* __restrict__ Bp, float* __restrict__ out) {
    __shared__ char smem[65536];   // buf b at (b<<15): A[0,16K) B[16K,32K)

    const int tid  = threadIdx.x;
    const int lane = tid & 63;
    const int wid  = tid >> 6;
    const int wm   = wid >> 1, wn = wid & 1;
    const int l15  = lane & 15, lg = lane >> 4;

    const int bid = blockIdx.x;          // 512
    const int s   = bid & 7;             // slab == XCD (round-robin dispatch)
    const int mn  = bid >> 3;            // 0..63
    const int mt  = mn >> 1, nt = mn & 1;
    const int t0  = s * 256;
    const int ntile = (s == 7) ? 260 : 256;   // slab 7 absorbs the 4 b2 tiles
    const int row_base = mt * 128;

    const int cc = tid & 7;              // A-staging: 16B chunk in row
    const int r0 = tid >> 3;             // A-staging: base row 0..31

    f32x4 acc[4][4];
#pragma unroll
    for (int i = 0; i < 4; ++i)
#pragma unroll
        for (int j = 0; j < 4; ++j)
#pragma unroll
            for (int q = 0; q < 4; ++q) acc[i][j][q] = 0.0f;

    auto stage = [&](int buf, int t) {
        char* sA = smem + (buf << 15);
        char* sB = sA + 16384;
        // B half-tile: linear 16KB global->LDS (swizzle pre-baked in source)
        const char* gsrc = (const char*)Bp + (size_t)t * TILE_BYTES + (nt << 14);
#pragma unroll
        for (int q = 0; q < 4; ++q) {
            int off = wid * 4096 + q * 1024;
            __builtin_amdgcn_global_load_lds(
                (const __attribute__((address_space(1))) void*)(gsrc + off + lane * 16),
                (__attribute__((address_space(3))) void*)(sB + off), 16, 0, 0);
        }
        // A tile: a[r][c] = scale(row, t>>2) * h[row, ((t&3)<<6)+c]
        int k  = t >> 2;
        int i0 = (t & 3) << 6;
        bool use_hyp = (k < 512);        // k==512 <=> b2 rows (scale 1)
#pragma unroll
        for (int j = 0; j < 4; ++j) {
            int r    = r0 + j * 32;
            int grow = row_base + r;
            float sc = use_hyp ? hyp[grow * 512 + k] : 1.0f;
            const f32x4* hp = (const f32x4*)(h + grow * 256 + i0 + cc * 8);
            f32x4 h0 = hp[0], h1 = hp[1];
            bf16x8 v;
            v[0] = (__bf16)(sc * h0[0]); v[1] = (__bf16)(sc * h0[1]);
            v[2] = (__bf16)(sc * h0[2]); v[3] = (__bf16)(sc * h0[3]);
            v[4] = (__bf16)(sc * h1[0]); v[5] = (__bf16)(sc * h1[1]);
            v[6] = (__bf16)(sc * h1[2]); v[7] = (__bf16)(sc * h1[3]);
            int off = (r * 128 + cc * 16) ^ ((r & 7) << 4);
            *(bf16x8*)(sA + off) = v;
        }
    };

    // prologue: fill buf0
    stage(0, t0);
    __syncthreads();

    for (int it = 0; it < ntile; ++it) {
        int cur = it & 1;
        // issue next tile's staging first: B-load latency + A-gen hide under compute
        if (it + 1 < ntile) stage(cur ^ 1, t0 + it + 1);

        const char* sA = smem + (cur << 15);
        const char* sB = sA + 16384;
#pragma unroll
        for (int ks = 0; ks < 2; ++ks) {
            bf16x8 af[4], bfr[4];
#pragma unroll
            for (int mf = 0; mf < 4; ++mf) {
                int row = wm * 64 + mf * 16 + l15;
                int off = (row * 128 + ks * 64 + lg * 16) ^ ((row & 7) << 4);
                af[mf] = *(const bf16x8*)(sA + off);
            }
#pragma unroll
            for (int nf = 0; nf < 4; ++nf) {
                int col = wn * 64 + nf * 16 + l15;
                int off = (col * 128 + ks * 64 + lg * 16) ^ ((col & 7) << 4);
                bfr[nf] = *(const bf16x8*)(sB + off);
            }
#pragma unroll
            for (int mf = 0; mf < 4; ++mf)
#pragma unroll
                for (int nf = 0; nf < 4; ++nf)
                    acc[mf][nf] = __builtin_amdgcn_mfma_f32_16x16x32_bf16(
                        af[mf], bfr[nf], acc[mf][nf], 0, 0, 0);
        }
        __syncthreads();   // drains vmcnt(0)+lgkmcnt(0): buf^1 staging complete
    }

    // ---- epilogue: atomic split-K accumulate (out pre-initialized with bias) ----
    int crow0 = row_base + wm * 64;
    int ccol0 = nt * 128 + wn * 64;
#pragma unroll
    for (int mf = 0; mf < 4; ++mf)
#pragma unroll
        for (int nf = 0; nf < 4; ++nf) {
            int col = ccol0 + nf * 16 + l15;
#pragma unroll
            for (int q = 0; q < 4; ++q) {
                int row = crow0 + mf * 16 + lg * 4 + q;
                atomicAdd(&out[row * 256 + col], acc[mf][nf][q]);
            }
        }
}

extern "C" void kernel_launch(void* const* d_in, const int* in_sizes, int n_in,
                              void* d_out, int out_size, void* d_ws, size_t ws_size,
                              hipStream_t stream) {
    const float* h    = (const float*)d_in[0];  // [4096,256]
    const float* z    = (const float*)d_in[1];  // [4096,128]
    const float* W1   = (const float*)d_in[2];  // [128,512]
    const float* b1   = (const float*)d_in[3];  // [512]
    const float* W2   = (const float*)d_in[4];  // [512,65536]
    const float* b2   = (const float*)d_in[5];  // [65536]
    const float* bias = (const float*)d_in[6];  // [1,256]
    float* out = (float*)d_out;                 // [4096,256] fp32

    float*    hyp = (float*)d_ws;                                   // 8 MB
    uint16_t* Bp  = (uint16_t*)((char*)d_ws + 8u * 1024u * 1024u);  // 67.2 MB

    k_pack    <<<KTILES, 256, 0, stream>>>(W2, b2, Bp);
    k_hyp     <<<4096,   256, 0, stream>>>(z, W1, b1, hyp);
    k_init_out<<<4096,   256, 0, stream>>>(bias, out);
    k_gemm    <<<512,    256, 0, stream>>>(h, hyp, Bp, out);
}

// Round 3
// 526.764 us; speedup vs baseline: 1.2394x; 1.2394x over previous
//
#include <hip/hip_runtime.h>
#include <hip/hip_bf16.h>
#include <stdint.h>

// out[b,o] = sum_{k,i} hyp[b,k]*h[b,i]*W2[k,i*256+o] + sum_i h[b,i]*b2[i*256+o] + bias[o]
// GEMM A[4096 x 131328] * B[131328 x 256] with A = diag(hyp_k) * H per k-group.
// Trick: A-LDS holds PURE h (static, written once); per-tile partial product is
// scaled by hyp in fp32 registers: acc += sc_k * (H_tile . B_tile).
// hypT[513][4096] (row 512 = ones) folds b2 in as k=512.
// ws: [0, 8.4MB) hypT fp32; [9MB, +67.2MB) packed bf16 B tiles (swizzled).

typedef __bf16 bf16x8 __attribute__((ext_vector_type(8)));
typedef float  f32x4  __attribute__((ext_vector_type(4)));

#define KTILES     2052
#define TILE_BYTES 32768          // 256 cols * 64 k * 2B
#define HYPT_OFF   (9u*1024u*1024u)

// ---------------- out = bias ----------------
__global__ void k_init_out(const float* __restrict__ bias, float* __restrict__ out) {
    int idx = blockIdx.x * 256 + threadIdx.x;
    out[idx] = bias[idx & 255];
}

// ---------------- hypT[k][b] = relu(z@W1+b1)^T; row 512 = 1.0 ----------------
__global__ void k_hypT(const float* __restrict__ z, const float* __restrict__ W1,
                       const float* __restrict__ b1, float* __restrict__ hypT) {
    if (blockIdx.x == 64) {                      // ones row (b2 scale)
        int t = threadIdx.x;
#pragma unroll
        for (int r = 0; r < 8; ++r) hypT[(size_t)512*4096 + r*512 + t] = 1.0f;
        return;
    }
    __shared__ float zs[64][128];
    int b0 = blockIdx.x * 64;
    int t  = threadIdx.x;                        // 512 threads; t == k
#pragma unroll
    for (int u = 0; u < 16; ++u) {
        int idx = u * 512 + t;
        zs[idx >> 7][idx & 127] = z[b0 * 128 + idx];
    }
    __syncthreads();
    float acc[64];
    float bk = b1[t];
#pragma unroll
    for (int b = 0; b < 64; ++b) acc[b] = bk;
    for (int c = 0; c < 128; ++c) {
        float w = W1[c * 512 + t];
#pragma unroll
        for (int b = 0; b < 64; ++b) acc[b] = fmaf(zs[b][c], w, acc[b]);
    }
    float* dst = hypT + (size_t)t * 4096 + b0;
#pragma unroll
    for (int v = 0; v < 16; ++v) {
        f32x4 o;
#pragma unroll
        for (int q = 0; q < 4; ++q) {
            float a = acc[v * 4 + q];
            o[q] = a > 0.f ? a : 0.f;
        }
        *(f32x4*)(dst + v * 4) = o;
    }
}

// ---------------- pack W2 (+b2) -> bf16 transposed+swizzled tiles ----------------
// element (kk, o) of tile t at byte (o*128 + kk*2) ^ ((o&7)<<4)
__global__ void k_pack(const float* __restrict__ W2, const float* __restrict__ b2,
                       uint16_t* __restrict__ Bp) {
    int t = blockIdx.x;
    int o = threadIdx.x;
    long row0 = (long)t * 64;
    const float* src = (t < 2048) ? (W2 + row0 * 256) : (b2 + (row0 - 131072) * 256);
    char* dst = (char*)Bp + (size_t)t * TILE_BYTES;
    int swz = (o & 7) << 4;
#pragma unroll
    for (int k8 = 0; k8 < 8; ++k8) {
        bf16x8 v;
#pragma unroll
        for (int q = 0; q < 8; ++q)
            v[q] = (__bf16)src[(k8 * 8 + q) * 256 + o];
        *(bf16x8*)(dst + ((o * 128 + k8 * 16) ^ swz)) = v;
    }
}

// ---------------- main GEMM: BM=128, BN=256, BK=64, 8 waves, 1 block/CU ----------------
// A-static (pure h, bf16, 64KB) + B double-buffer (2x32KB). grid 256 = 32 mt x 8 slabs.
// i0-major sweep: A-frags loop-invariant per 64-iter group (registers).
__global__ __launch_bounds__(512, 2) void k_gemm(
        const float* __restrict__ h, const float* __restrict__ hypT,
        const uint16_t* __restrict__ Bp, float* __restrict__ out) {
    __shared__ char smem[131072];   // [0,64K): A-static; [64K,+32K)x2: B dbuf

    const int tid  = threadIdx.x;
    const int lane = tid & 63;
    const int wid  = tid >> 6;            // 8 waves
    const int wm   = wid >> 2, wn = wid & 3;   // 2 x 4 wave grid, 64x64 each
    const int l15  = lane & 15, lg = lane >> 4;

    const int bid = blockIdx.x;           // 256 blocks
    const int s   = bid & 7;              // K-slab == XCD (round-robin dispatch)
    const int mt  = bid >> 3;             // 0..31
    const int k0  = s * 64;
    const int row_base = mt * 128;

    // ---- prologue: A-static = bf16(h[row_base..+128][0..256]), swizzled ----
    {
        int r  = tid >> 2;                // 0..127
        int cq = tid & 3;                 // 64-col quarter
        const float* hrow = h + (size_t)(row_base + r) * 256 + cq * 64;
        int swz = (r & 7) << 4;
#pragma unroll
        for (int u = 0; u < 8; ++u) {
            f32x4 a = ((const f32x4*)hrow)[u * 2];
            f32x4 b = ((const f32x4*)hrow)[u * 2 + 1];
            bf16x8 v;
            v[0] = (__bf16)a[0]; v[1] = (__bf16)a[1]; v[2] = (__bf16)a[2]; v[3] = (__bf16)a[3];
            v[4] = (__bf16)b[0]; v[5] = (__bf16)b[1]; v[6] = (__bf16)b[2]; v[7] = (__bf16)b[3];
            int c8 = cq * 8 + u;
            *(bf16x8*)(smem + ((r * 512 + c8 * 16) ^ swz)) = v;
        }
    }

    auto stage = [&](int buf, int t) {
        const char* gsrc = (const char*)Bp + (size_t)t * TILE_BYTES + wid * 4096 + lane * 16;
        char* ldst = smem + 65536 + (buf << 15) + wid * 4096;   // wave-uniform base
#pragma unroll
        for (int q = 0; q < 4; ++q)
            __builtin_amdgcn_global_load_lds(
                (const __attribute__((address_space(1))) void*)(gsrc + q * 1024),
                (__attribute__((address_space(3))) void*)(ldst + q * 1024), 16, 0, 0);
    };

    stage(0, k0 * 4);           // first tile (g=0, j=0)
    __syncthreads();            // A-static + buf0 ready

    f32x4 acc[4][4];
#pragma unroll
    for (int i = 0; i < 4; ++i)
#pragma unroll
        for (int j = 0; j < 4; ++j)
#pragma unroll
            for (int q = 0; q < 4; ++q) acc[i][j][q] = 0.0f;

    const f32x4 fzero = {0.f, 0.f, 0.f, 0.f};
    const float* scbase = hypT + row_base + wm * 64 + lg * 4;

    for (int g2 = 0; g2 < 4; ++g2) {
        // A-frags for this i0 group: loop-invariant, cached in registers
        bf16x8 af[4][2];
#pragma unroll
        for (int mf = 0; mf < 4; ++mf)
#pragma unroll
            for (int ks = 0; ks < 2; ++ks) {
                int row = wm * 64 + mf * 16 + l15;
                af[mf][ks] = *(const bf16x8*)(smem +
                    ((row * 512 + g2 * 128 + ks * 64 + lg * 16) ^ ((row & 7) << 4)));
            }
#pragma unroll 2
        for (int j = 0; j < 64; ++j) {
            int k   = k0 + j;
            int buf = j & 1;
            // stage next tile into buf^1
            int t  = k * 4 + g2;
            int tn = (j < 63) ? t + 4 : (g2 < 3 ? k0 * 4 + g2 + 1 : 2048);
            if (j < 63 || g2 < 3 || s == 7) stage(buf ^ 1, tn);

            // sc (hypT row k, this wave's 64 rows) — L1-hot
            const float* hp = scbase + (size_t)k * 4096;
            f32x4 scv[4];
#pragma unroll
            for (int mf = 0; mf < 4; ++mf) scv[mf] = *(const f32x4*)(hp + mf * 16);

            const char* sB = smem + 65536 + (buf << 15);
            bf16x8 bf0[4], bf1[4];
#pragma unroll
            for (int nf = 0; nf < 4; ++nf) {
                int col = wn * 64 + nf * 16 + l15;
                int swz = (col & 7) << 4;
                bf0[nf] = *(const bf16x8*)(sB + ((col * 128 + lg * 16) ^ swz));
                bf1[nf] = *(const bf16x8*)(sB + ((col * 128 + 64 + lg * 16) ^ swz));
            }
#pragma unroll
            for (int mf = 0; mf < 4; ++mf) {
                f32x4 part[4];
#pragma unroll
                for (int nf = 0; nf < 4; ++nf)
                    part[nf] = __builtin_amdgcn_mfma_f32_16x16x32_bf16(af[mf][0], bf0[nf], fzero, 0, 0, 0);
#pragma unroll
                for (int nf = 0; nf < 4; ++nf)
                    part[nf] = __builtin_amdgcn_mfma_f32_16x16x32_bf16(af[mf][1], bf1[nf], part[nf], 0, 0, 0);
#pragma unroll
                for (int nf = 0; nf < 4; ++nf)
#pragma unroll
                    for (int q = 0; q < 4; ++q)
                        acc[mf][nf][q] = fmaf(scv[mf][q], part[nf][q], acc[mf][nf][q]);
            }
            __syncthreads();   // drains vmcnt: buf^1 staging complete
        }
    }

    // ---- tail: slab 7 also owns the b2 rows (k=512, scale 1), tiles 2048..2051 ----
    if (s == 7) {
#pragma unroll
        for (int g2 = 0; g2 < 4; ++g2) {
            int buf = g2 & 1;
            bf16x8 af[4][2];
#pragma unroll
            for (int mf = 0; mf < 4; ++mf)
#pragma unroll
                for (int ks = 0; ks < 2; ++ks) {
                    int row = wm * 64 + mf * 16 + l15;
                    af[mf][ks] = *(const bf16x8*)(smem +
                        ((row * 512 + g2 * 128 + ks * 64 + lg * 16) ^ ((row & 7) << 4)));
                }
            if (g2 < 3) stage(buf ^ 1, 2049 + g2);
            const char* sB = smem + 65536 + (buf << 15);
            bf16x8 bf0[4], bf1[4];
#pragma unroll
            for (int nf = 0; nf < 4; ++nf) {
                int col = wn * 64 + nf * 16 + l15;
                int swz = (col & 7) << 4;
                bf0[nf] = *(const bf16x8*)(sB + ((col * 128 + lg * 16) ^ swz));
                bf1[nf] = *(const bf16x8*)(sB + ((col * 128 + 64 + lg * 16) ^ swz));
            }
#pragma unroll
            for (int mf = 0; mf < 4; ++mf) {
                f32x4 part[4];
#pragma unroll
                for (int nf = 0; nf < 4; ++nf)
                    part[nf] = __builtin_amdgcn_mfma_f32_16x16x32_bf16(af[mf][0], bf0[nf], fzero, 0, 0, 0);
#pragma unroll
                for (int nf = 0; nf < 4; ++nf)
                    part[nf] = __builtin_amdgcn_mfma_f32_16x16x32_bf16(af[mf][1], bf1[nf], part[nf], 0, 0, 0);
#pragma unroll
                for (int nf = 0; nf < 4; ++nf)
#pragma unroll
                    for (int q = 0; q < 4; ++q)
                        acc[mf][nf][q] += part[nf][q];
            }
            __syncthreads();
        }
    }

    // ---- epilogue: atomic split-K accumulate (out pre-initialized with bias) ----
    int crow0 = row_base + wm * 64;
    int ccol0 = wn * 64;
#pragma unroll
    for (int mf = 0; mf < 4; ++mf)
#pragma unroll
        for (int nf = 0; nf < 4; ++nf) {
            int col = ccol0 + nf * 16 + l15;
#pragma unroll
            for (int q = 0; q < 4; ++q) {
                int row = crow0 + mf * 16 + lg * 4 + q;   // C/D: col=lane&15, row=(lane>>4)*4+q
                atomicAdd(&out[row * 256 + col], acc[mf][nf][q]);
            }
        }
}

extern "C" void kernel_launch(void* const* d_in, const int* in_sizes, int n_in,
                              void* d_out, int out_size, void* d_ws, size_t ws_size,
                              hipStream_t stream) {
    const float* h    = (const float*)d_in[0];  // [4096,256]
    const float* z    = (const float*)d_in[1];  // [4096,128]
    const float* W1   = (const float*)d_in[2];  // [128,512]
    const float* b1   = (const float*)d_in[3];  // [512]
    const float* W2   = (const float*)d_in[4];  // [512,65536]
    const float* b2   = (const float*)d_in[5];  // [65536]
    const float* bias = (const float*)d_in[6];  // [1,256]
    float* out = (float*)d_out;                 // [4096,256] fp32

    float*    hypT = (float*)d_ws;                          // 513*4096*4 = 8.4 MB
    uint16_t* Bp   = (uint16_t*)((char*)d_ws + HYPT_OFF);   // 67.2 MB

    k_pack    <<<KTILES, 256, 0, stream>>>(W2, b2, Bp);
    k_hypT    <<<65,     512, 0, stream>>>(z, W1, b1, hypT);
    k_init_out<<<4096,   256, 0, stream>>>(bias, out);
    k_gemm    <<<256,    512, 0, stream>>>(h, hypT, Bp, out);
}

// Round 4
// 358.571 us; speedup vs baseline: 1.8208x; 1.4691x over previous
//
#include <hip/hip_runtime.h>
#include <hip/hip_bf16.h>
#include <stdint.h>

// out[b,o] = sum_{k,i} hyp[b,k]*h[b,i]*W2[k,i*256+o] + sum_i h[b,i]*b2[i*256+o] + bias[o]
// GEMM A[4096 x 131328] * B[131328 x 256], A = diag(hyp_k)*H per k-group.
// A never hits LDS: af frags live in regs per i0-group; partial products are scaled
// by hyp in fp32 (acc += sc * (H_tile . B_tile)); hyp scales come from a 32KB LDS slab.
// B = W2 flat, bf16, pre-packed transposed+swizzled; streamed via global_load_lds into
// a 3-deep LDS ring with counted vmcnt(4) + single raw s_barrier per iteration (T3/T4/T5).
// ws: [0, 8.4MB) hypT fp32 [513][4096] (row 512 = ones, folds b2); [9MB, +67.2MB) packed B.

typedef __bf16 bf16x8 __attribute__((ext_vector_type(8)));
typedef float  f32x4  __attribute__((ext_vector_type(4)));

#define KTILES     2052
#define TILE_BYTES 32768          // 256 cols * 64 k * 2B
#define HYPT_OFF   (9u*1024u*1024u)

// ---------------- out = bias ----------------
__global__ void k_init_out(const float* __restrict__ bias, float* __restrict__ out) {
    int idx = blockIdx.x * 256 + threadIdx.x;
    out[idx] = bias[idx & 255];
}

// ---------------- hypT[k][b] = relu(z@W1+b1)^T; row 512 = 1.0 ----------------
__global__ void k_hypT(const float* __restrict__ z, const float* __restrict__ W1,
                       const float* __restrict__ b1, float* __restrict__ hypT) {
    int blk = blockIdx.x;
    int t   = threadIdx.x;                       // 512 threads; t == k
    if (blk == 128) {                            // ones row (b2 scale)
#pragma unroll
        for (int r = 0; r < 8; ++r) hypT[(size_t)512*4096 + r*512 + t] = 1.0f;
        return;
    }
    __shared__ float zs[32][128];
    int b0 = blk * 32;
#pragma unroll
    for (int u = 0; u < 8; ++u) {
        int idx = u * 512 + t;
        zs[idx >> 7][idx & 127] = z[b0 * 128 + idx];
    }
    __syncthreads();
    float acc[32];
    float bk = b1[t];
#pragma unroll
    for (int b = 0; b < 32; ++b) acc[b] = bk;
    for (int c = 0; c < 128; ++c) {
        float w = W1[c * 512 + t];
#pragma unroll
        for (int b = 0; b < 32; ++b) acc[b] = fmaf(zs[b][c], w, acc[b]);
    }
    float* dst = hypT + (size_t)t * 4096 + b0;
#pragma unroll
    for (int v = 0; v < 8; ++v) {
        f32x4 o;
#pragma unroll
        for (int q = 0; q < 4; ++q) {
            float a = acc[v * 4 + q];
            o[q] = a > 0.f ? a : 0.f;
        }
        *(f32x4*)(dst + v * 4) = o;
    }
}

// ---------------- pack W2 (+b2) -> bf16 transposed+swizzled tiles ----------------
// dst element (kk,o) at byte (o*128 + kk*2) ^ ((o&7)<<4). Build image in LDS
// (coalesced fp32 reads), then stream out with coalesced 16B stores.
__global__ void k_pack(const float* __restrict__ W2, const float* __restrict__ b2,
                       uint16_t* __restrict__ Bp) {
    __shared__ char tile[TILE_BYTES];
    int t   = blockIdx.x;
    int tid = threadIdx.x;        // 256
    long row0 = (long)t * 64;
    const float* src = (t < 2048) ? (W2 + row0 * 256) : (b2 + (row0 - 131072) * 256);
#pragma unroll
    for (int u = 0; u < 16; ++u) {
        int f = (u * 256 + tid) * 4;              // flat fp32 idx, coalesced
        f32x4 v = *(const f32x4*)(src + f);
        int kk = f >> 8;
        int o0 = f & 255;
#pragma unroll
        for (int j = 0; j < 4; ++j) {
            int o = o0 + j;
            int addr = (o * 128 + kk * 2) ^ ((o & 7) << 4);
            *(__bf16*)(tile + addr) = (__bf16)v[j];
        }
    }
    __syncthreads();
    char* dst = (char*)Bp + (size_t)t * TILE_BYTES;
#pragma unroll
    for (int v = 0; v < 8; ++v) {
        int off = (v * 256 + tid) * 16;           // coalesced 16B copy out
        *(f32x4*)(dst + off) = *(const f32x4*)(tile + off);
    }
}

// ---------------- main GEMM: BM=128, BN=256, 8 waves, 3-deep ring, 1 barrier/iter ----
// grid 256 = 8 K-slabs (==XCD) x 32 mt; LDS = 3x32KB B ring + 32KB hyp slab = 128KB.
__global__ __launch_bounds__(512, 2) void k_gemm(
        const float* __restrict__ h, const float* __restrict__ hypT,
        const uint16_t* __restrict__ Bp, float* __restrict__ out) {
    __shared__ char smem[131072];

    const int tid  = threadIdx.x;
    const int lane = tid & 63;
    const int wid  = tid >> 6;                 // 8 waves
    const int wm   = wid >> 2, wn = wid & 3;   // 2 x 4 wave grid, 64x64 out each
    const int l15  = lane & 15, lg = lane >> 4;

    const int bid = blockIdx.x;                // 256
    const int s   = bid & 7;                   // K-slab == XCD
    const int mt  = bid >> 3;                  // 0..31
    const int k0  = s * 64;
    const int row_base = mt * 128;
    const int NT  = (s == 7) ? 260 : 256;      // slab 7 owns the 4 b2 tiles

    float* shyp = (float*)(smem + 98304);      // [64 kk][128 r] fp32

    // ---- prologue: hyp slab -> LDS (one-time) ----
#pragma unroll
    for (int u = 0; u < 4; ++u) {
        int f  = (u * 512 + tid) * 4;          // 8192 floats
        int kk = f >> 7;
        int r  = f & 127;
        *(f32x4*)(shyp + kk * 128 + r) =
            *(const f32x4*)(hypT + (size_t)(k0 + kk) * 4096 + row_base + r);
    }

    auto tile_of = [&](int idx) {
        return (idx < 256) ? ((k0 + (idx & 63)) * 4 + (idx >> 6)) : (2048 + idx - 256);
    };
    auto stage = [&](int bufoff, int t) {
        const char* gsrc = (const char*)Bp + (size_t)t * TILE_BYTES + wid * 4096 + lane * 16;
        char* ldst = smem + bufoff + wid * 4096;    // wave-uniform base + lane*16 implicit
#pragma unroll
        for (int q = 0; q < 4; ++q)
            __builtin_amdgcn_global_load_lds(
                (const __attribute__((address_space(1))) void*)(gsrc + q * 1024),
                (__attribute__((address_space(3))) void*)(ldst + q * 1024), 16, 0, 0);
    };

    stage(0,     tile_of(0));
    stage(32768, tile_of(1));
    asm volatile("s_waitcnt vmcnt(4) lgkmcnt(0)" ::: "memory");  // tile0 + shyp done
    __builtin_amdgcn_s_barrier();

    f32x4 acc[4][4];
#pragma unroll
    for (int i = 0; i < 4; ++i)
#pragma unroll
        for (int j = 0; j < 4; ++j)
#pragma unroll
            for (int q = 0; q < 4; ++q) acc[i][j][q] = 0.0f;

    const f32x4 fzero = {0.f, 0.f, 0.f, 0.f};
    int boff_read = 0, boff_next = 32768, boff_stage = 65536;

    for (int G = 0; G < 8; ++G) {              // 0..3 main (64 iters), 4..7 b2 tail (s==7)
        if (G >= 4 && s != 7) break;
        int niter = (G < 4) ? 64 : 1;

        // A-frags for this i0-group: global -> regs (4-8x per kernel, vmcnt drain OK here)
        bf16x8 af[4][2];
#pragma unroll
        for (int mf = 0; mf < 4; ++mf)
#pragma unroll
            for (int ks = 0; ks < 2; ++ks) {
                const float* hp = h + (size_t)(row_base + wm * 64 + mf * 16 + l15) * 256
                                    + (G & 3) * 64 + ks * 32 + lg * 8;
                f32x4 a = *(const f32x4*)hp, b = *(const f32x4*)(hp + 4);
                bf16x8 v;
                v[0] = (__bf16)a[0]; v[1] = (__bf16)a[1]; v[2] = (__bf16)a[2]; v[3] = (__bf16)a[3];
                v[4] = (__bf16)b[0]; v[5] = (__bf16)b[1]; v[6] = (__bf16)b[2]; v[7] = (__bf16)b[3];
                af[mf][ks] = v;
            }

        for (int jj = 0; jj < niter; ++jj) {
            int idx = (G < 4) ? G * 64 + jj : 256 + (G - 4);

            // 1. B-frags from current ring buffer (swizzled ds_read_b128)
            const char* sB = smem + boff_read;
            bf16x8 bf0[4], bf1[4];
#pragma unroll
            for (int nf = 0; nf < 4; ++nf) {
                int col = wn * 64 + nf * 16 + l15;
                int swz = (col & 7) << 4;
                bf0[nf] = *(const bf16x8*)(sB + ((col * 128 + lg * 16) ^ swz));
                bf1[nf] = *(const bf16x8*)(sB + ((col * 128 + 64 + lg * 16) ^ swz));
            }
            // hyp scales from LDS slab (broadcast reads, conflict-free)
            f32x4 scv[4];
            if (idx < 256) {
#pragma unroll
                for (int mf = 0; mf < 4; ++mf)
                    scv[mf] = *(const f32x4*)(shyp + jj * 128 + wm * 64 + mf * 16 + lg * 4);
            } else {
#pragma unroll
                for (int mf = 0; mf < 4; ++mf) scv[mf] = {1.f, 1.f, 1.f, 1.f};
            }

            // 2. prefetch idx+2 into the buffer freed last iteration
            bool do_stage = (idx + 2 < NT);
            if (do_stage) stage(boff_stage, tile_of(idx + 2));

            // 3. MFMA + fp32 scale-accumulate
            __builtin_amdgcn_s_setprio(1);
#pragma unroll
            for (int mf = 0; mf < 4; ++mf) {
                f32x4 part[4];
#pragma unroll
                for (int nf = 0; nf < 4; ++nf)
                    part[nf] = __builtin_amdgcn_mfma_f32_16x16x32_bf16(af[mf][0], bf0[nf], fzero, 0, 0, 0);
#pragma unroll
                for (int nf = 0; nf < 4; ++nf)
                    part[nf] = __builtin_amdgcn_mfma_f32_16x16x32_bf16(af[mf][1], bf1[nf], part[nf], 0, 0, 0);
#pragma unroll
                for (int nf = 0; nf < 4; ++nf)
#pragma unroll
                    for (int q = 0; q < 4; ++q)
                        acc[mf][nf][q] = fmaf(scv[mf][q], part[nf][q], acc[mf][nf][q]);
            }
            __builtin_amdgcn_s_setprio(0);

            // 4. counted wait (keep idx+2's loads in flight!) + single barrier
            if (do_stage) asm volatile("s_waitcnt vmcnt(4)" ::: "memory");
            else          asm volatile("s_waitcnt vmcnt(0)" ::: "memory");
            __builtin_amdgcn_s_barrier();

            int tmp = boff_read; boff_read = boff_next; boff_next = boff_stage; boff_stage = tmp;
        }
    }

    // ---- epilogue: atomic split-K accumulate (out pre-initialized with bias) ----
    int crow0 = row_base + wm * 64;
    int ccol0 = wn * 64;
#pragma unroll
    for (int mf = 0; mf < 4; ++mf)
#pragma unroll
        for (int nf = 0; nf < 4; ++nf) {
            int col = ccol0 + nf * 16 + l15;
#pragma unroll
            for (int q = 0; q < 4; ++q) {
                int row = crow0 + mf * 16 + lg * 4 + q;   // C/D: col=lane&15, row=(lane>>4)*4+q
                atomicAdd(&out[row * 256 + col], acc[mf][nf][q]);
            }
        }
}

extern "C" void kernel_launch(void* const* d_in, const int* in_sizes, int n_in,
                              void* d_out, int out_size, void* d_ws, size_t ws_size,
                              hipStream_t stream) {
    const float* h    = (const float*)d_in[0];  // [4096,256]
    const float* z    = (const float*)d_in[1];  // [4096,128]
    const float* W1   = (const float*)d_in[2];  // [128,512]
    const float* b1   = (const float*)d_in[3];  // [512]
    const float* W2   = (const float*)d_in[4];  // [512,65536]
    const float* b2   = (const float*)d_in[5];  // [65536]
    const float* bias = (const float*)d_in[6];  // [1,256]
    float* out = (float*)d_out;                 // [4096,256] fp32

    float*    hypT = (float*)d_ws;                          // 513*4096*4 = 8.4 MB
    uint16_t* Bp   = (uint16_t*)((char*)d_ws + HYPT_OFF);   // 67.2 MB

    k_pack    <<<KTILES, 256, 0, stream>>>(W2, b2, Bp);
    k_hypT    <<<129,    512, 0, stream>>>(z, W1, b1, hypT);
    k_init_out<<<4096,   256, 0, stream>>>(bias, out);
    k_gemm    <<<256,    512, 0, stream>>>(h, hypT, Bp, out);
}